// Round 11
// baseline (192.874 us; speedup 1.0000x reference)
//
#include <hip/hip_runtime.h>
#include <hip/hip_bf16.h>
#include <math.h>

// ---------------------------------------------------------------------------
// Problem constants
// ---------------------------------------------------------------------------
constexpr int B = 8;
constexpr int N = 2048;
constexpr int KNN = 20;
constexpr int H = 128;
constexpr int P = 3 * N;  // 6144 pixels per batch

// ws layout (float offsets)
constexpr int OSB2   = 0;         // published sb for layer2 [B][768]
constexpr int OWT2   = 8448;      // W2/D2 second-half TRANSPOSED [c<128][m<256]
constexpr int OWT3   = 41216;     // W3/D3 second-half transposed
constexpr int OPS1   = 73984;     // poolsum1 shadows [8][B][128][3] = 24576
constexpr int OPS2   = 98560;     // poolsum2 shadows = 24576
constexpr int OOUTS  = 123136;    // out shadows [8][B][384] = 24576
constexpr int OBAR   = 147712;    // barrier counters/flags (1024 f reserved)
constexpr int OSB3   = 148736;    // published sb for layer3 [B][768]
constexpr int OWB1   = 160000;    // Wbig1 bf16 hi/lo, FRAGMENT-MAJOR (16384 f)
constexpr int OWB2   = 176384;    // Wbig2 fragment-major (32768 f)
constexpr int OWB3   = 209152;    // Wbig3 fragment-major (32768 f)

constexpr int ZERO_BASE = OPS1;   // zeroed region = ps1+ps2+outs+barriers
constexpr int ZERO_CNT  = 74752;  // 73728 shadows + 1024 barrier words
constexpr int PREP_BLOCKS = (ZERO_CNT + 255) / 256;  // 292

constexpr int GRID_VNT  = 1024;   // 4 blocks/CU x 256 CU, exactly co-resident
constexpr int BLK_PER_B = 128;    // blocks per batch (per-batch barrier target)

typedef __attribute__((ext_vector_type(8))) short bf16x8;
typedef __attribute__((ext_vector_type(4))) float f32x4;

__device__ __forceinline__ unsigned short f2bf(float x) {
  __hip_bfloat16 h = __float2bfloat16(x);
  return *(unsigned short*)&h;
}
__device__ __forceinline__ float bf2f(unsigned short u) {
  __hip_bfloat16 h;
  *(unsigned short*)&h = u;
  return __bfloat162float(h);
}
// pack x as (hi, lo) bf16 pair in one uint (hi at lower address)
__device__ __forceinline__ unsigned int packhl(float x) {
  unsigned short hi = f2bf(x);
  float lo = x - bf2f(hi);
  unsigned short ls = f2bf(lo);
  return (unsigned)hi | ((unsigned)ls << 16);
}

// coherent-point read/write (no cache-maintenance instructions)
__device__ __forceinline__ float cohload(const float* p) {
  return __hip_atomic_load(p, __ATOMIC_RELAXED, __HIP_MEMORY_SCOPE_AGENT);
}
__device__ __forceinline__ void cohstore(float* p, float v) {
  __hip_atomic_store(p, v, __ATOMIC_RELAXED, __HIP_MEMORY_SCOPE_AGENT);
}

// ---------------------------------------------------------------------------
// Wave-wide bitonic sort of 64 u64 keys, descending.
// ---------------------------------------------------------------------------
__device__ __forceinline__ void wave_sort_key(unsigned long long& k, int lane) {
#pragma unroll
  for (int kk = 2; kk <= 64; kk <<= 1) {
#pragma unroll
    for (int j = kk >> 1; j > 0; j >>= 1) {
      unsigned long long pk =
          (unsigned long long)__shfl_xor((long long)k, j);
      bool iam_lower   = (lane & j) == 0;
      bool dir_desc    = (lane & kk) == 0;
      bool p_better    = pk > k;
      bool want_better = (dir_desc == iam_lower);
      k = (p_better == want_better) ? pk : k;
    }
  }
}

// ---------------------------------------------------------------------------
// K1: prep — zero shadows/counters + pack weights.  Runs BEFORE the fused
// kernel; the kernel boundary orders zeroing/packing ahead of all barrier
// arrivals and Wb reads.
// ---------------------------------------------------------------------------
__global__ __launch_bounds__(256) void prep_kernel(
    const float* __restrict__ W1, const float* __restrict__ D1,
    const float* __restrict__ W2, const float* __restrict__ D2,
    const float* __restrict__ W3, const float* __restrict__ D3,
    float* __restrict__ ws) {
  int tid = threadIdx.x;
  int bid = blockIdx.x;
  {
    int zi = bid * 256 + tid;
    if (zi < ZERO_CNT) ws[ZERO_BASE + zi] = 0.f;
  }
  if (bid < 96) {
    int wv = tid >> 6, lane = tid & 63;
#pragma unroll
    for (int r = 0; r < 2; ++r) {
      int rr = bid * 8 + wv * 2 + r;  // 0..767
      const float* src;
      float* tdst = nullptr;
      unsigned int* pdst;
      int C, Cpack;
      bool norm;
      if (rr < 128)      { src = W1 + rr * 64;            C = 64;  Cpack = 64;  norm = true;
                           pdst = (unsigned int*)(ws + OWB1) + rr * 16; }
      else if (rr < 256) { int m = rr - 128; src = D1 + m * 64;  C = 64;  Cpack = 64;  norm = false;
                           pdst = (unsigned int*)(ws + OWB1) + (m + 128) * 16; }
      else if (rr < 384) { int m = rr - 256; src = W2 + m * 256; C = 256; Cpack = 128; norm = true;
                           pdst = (unsigned int*)(ws + OWB2) + m * 16; tdst = ws + OWT2 + m; }
      else if (rr < 512) { int m = rr - 384; src = D2 + m * 256; C = 256; Cpack = 128; norm = false;
                           pdst = (unsigned int*)(ws + OWB2) + (m + 128) * 16; tdst = ws + OWT2 + 128 + m; }
      else if (rr < 640) { int m = rr - 512; src = W3 + m * 256; C = 256; Cpack = 128; norm = true;
                           pdst = (unsigned int*)(ws + OWB3) + m * 16; tdst = ws + OWT3 + m; }
      else               { int m = rr - 640; src = D3 + m * 256; C = 256; Cpack = 128; norm = false;
                           pdst = (unsigned int*)(ws + OWB3) + (m + 128) * 16; tdst = ws + OWT3 + 128 + m; }
      float s = 1.f;
      if (norm) {
        float a = 0.f;
        for (int i = lane; i < C; i += 64) a += src[i];
#pragma unroll
        for (int off = 32; off > 0; off >>= 1) a += __shfl_xor(a, off);
        s = a;
      }
      for (int i = lane; i < C; i += 64) {
        float val = src[i] / s;  // exact when s==1
        if (i < Cpack) pdst[(i >> 4) * 4096 + (i & 15)] = packhl(val);
        if (tdst && i >= 128) tdst[(i - 128) * 256] = val;
      }
    }
  }
}

// ---------------------------------------------------------------------------
// Shared VNT layer body — 512-thread (8-wave) variant.  Each wave owns 16
// output rows (o = 16*w + 4*q + r); the former t-loop is distributed across
// waves, so every MFMA chain / accumulation order / epilogue element is
// bit-identical to the verified 4-wave version.  Staging/reduce/repack loops
// stride 512; the 256-row bias compute runs under if(tid<256) with barriers
// outside the conditional.  In-place repack valid: LDO*4 B == 264*2 B == 528.
// ---------------------------------------------------------------------------
template <int K2, bool HASPOOL, bool LAST>
__device__ __forceinline__ void vnt_layer_body(
    unsigned short* xt, float* sb, float* spool,
    const unsigned short* __restrict__ Wb,
    const float* __restrict__ ps, const float* __restrict__ Wt,
    float* __restrict__ sbg, unsigned int* sbflag,
    float* __restrict__ pool, float* __restrict__ outs,
    unsigned int* wait_cnt, unsigned int* arrive_cnt,
    int b, int nt, int p0, int tid) {
  constexpr int KS = K2 / 32;
  constexpr int LDR = K2 + 8;   // halves; X-tile row stride
  constexpr int LDO = 132;      // floats; out-tile row stride
  float* ot = (float*)xt;
  int w = tid >> 6, lane = tid & 63;   // w in 0..7
  int q = lane >> 4, cl = lane & 15;

  // first A-fragments: global, LDS-independent -> issue before wait/barrier
  bf16x8 acur[2], anxt[2];
#pragma unroll
  for (int pd = 0; pd < 2; ++pd)
    acur[pd] = *(const bf16x8*)(Wb +
        (size_t)(16 * w + 128 * pd + cl) * 32 + q * 8);

  if constexpr (HASPOOL) {
    if (nt == 0) {
      // ---- leader: wait for all batch peers' pool-adds --------------------
      if (tid == 0) {
        while (__hip_atomic_load(wait_cnt, __ATOMIC_RELAXED,
                                 __HIP_MEMORY_SCOPE_AGENT) < (unsigned)BLK_PER_B) {
          __builtin_amdgcn_s_sleep(2);
        }
      }
      __syncthreads();  // wait done + tile visible
      for (int i = tid; i < 384; i += 512) {
        float x = 0.f;
#pragma unroll
        for (int k = 0; k < 8; ++k)
          x += cohload(&ps[k * 3072 + b * 384 + i]);
        spool[i] = x * (1.f / 2048.f);
      }
      __syncthreads();
      // bias: thread == stacked row m (0..127 = Wn, 128..255 = D)
      if (tid < 256) {
        float s0 = 0.f, s1 = 0.f, s2 = 0.f;
#pragma unroll 16
        for (int c = 0; c < 128; ++c) {
          float x = Wt[c * 256 + tid];
          s0 = fmaf(x, spool[c * 3 + 0], s0);
          s1 = fmaf(x, spool[c * 3 + 1], s1);
          s2 = fmaf(x, spool[c * 3 + 2], s2);
        }
        sb[tid * 3 + 0] = s0;
        sb[tid * 3 + 1] = s1;
        sb[tid * 3 + 2] = s2;
        cohstore(&sbg[tid * 3 + 0], s0);   // publish to batch peers
        cohstore(&sbg[tid * 3 + 1], s1);
        cohstore(&sbg[tid * 3 + 2], s2);
      }
      __syncthreads();  // drains publish stores (vmcnt 0) + sb LDS visible
      if (tid == 0)
        __hip_atomic_fetch_add(sbflag, 1u, __ATOMIC_RELAXED,
                               __HIP_MEMORY_SCOPE_AGENT);
    } else {
      // ---- follower: wait for the leader's published bias -----------------
      if (tid == 0) {
        while (__hip_atomic_load(sbflag, __ATOMIC_RELAXED,
                                 __HIP_MEMORY_SCOPE_AGENT) < 1u) {
          __builtin_amdgcn_s_sleep(2);
        }
      }
      __syncthreads();  // flag seen + tile visible
      for (int i = tid; i < 768; i += 512) sb[i] = cohload(&sbg[i]);
      __syncthreads();  // sb in LDS for all waves
    }
  } else {
    __syncthreads();  // tile visible to all waves
  }

  f32x4 acc[2][3] = {};  // [pd][v]

#pragma unroll
  for (int ks = 0; ks < KS; ++ks) {
    if (ks + 1 < KS) {
#pragma unroll
      for (int pd = 0; pd < 2; ++pd)
        anxt[pd] = *(const bf16x8*)(Wb +
            (size_t)(16 * w + 128 * pd + cl) * 32 + q * 8 +
            (ks + 1) * 8192);
    }
    bf16x8 bb[3];
#pragma unroll
    for (int v = 0; v < 3; ++v)
      bb[v] = *(const bf16x8*)(xt + (v * 16 + cl) * LDR + ks * 32 + q * 8);
#pragma unroll
    for (int pd = 0; pd < 2; ++pd)
#pragma unroll
      for (int v = 0; v < 3; ++v)
        acc[pd][v] = __builtin_amdgcn_mfma_f32_16x16x32_bf16(
            acur[pd], bb[v], acc[pd][v], 0, 0, 0);
#pragma unroll
    for (int pd = 0; pd < 2; ++pd)
      acur[pd] = anxt[pd];
  }
  __syncthreads();  // X-tile dead; buffer becomes the fp32 out-tile

  {
    float res[3][4];
#pragma unroll
    for (int r = 0; r < 4; ++r) {
      int o = 16 * w + 4 * q + r;
      float pv[3], dvv[3];
#pragma unroll
      for (int v = 0; v < 3; ++v) {
        pv[v] = acc[0][v][r] + (HASPOOL ? sb[o * 3 + v] : 0.f);
        dvv[v] = acc[1][v][r] + (HASPOOL ? sb[(128 + o) * 3 + v] : 0.f);
      }
      float dot = fmaf(pv[0], dvv[0], fmaf(pv[1], dvv[1], pv[2] * dvv[2]));
      float dns = fmaf(dvv[0], dvv[0], fmaf(dvv[1], dvv[1], dvv[2] * dvv[2]));
      float f = (dot < 0.f) ? dot / (dns + 1e-6f) : 0.f;
#pragma unroll
      for (int v = 0; v < 3; ++v) res[v][r] = pv[v] - f * dvv[v];
    }
    int o0 = 16 * w + 4 * q;
#pragma unroll
    for (int v = 0; v < 3; ++v) {
      f32x4 rv = {res[v][0], res[v][1], res[v][2], res[v][3]};
      *(f32x4*)(ot + (v * 16 + cl) * LDO + o0) = rv;
    }
  }
  __syncthreads();

  int shadow = (nt & 7) * 3072;
  for (int s = tid; s < 384; s += 512) {
    int o = s / 3, v = s % 3;
    float a2 = 0.f;
#pragma unroll
    for (int c = 0; c < 16; ++c) a2 += ot[(v * 16 + c) * LDO + o];
    if (LAST) atomicAdd(outs + shadow + b * 384 + s, a2);
    else      atomicAdd(pool + shadow + b * 384 + s, a2);
  }

  // drain this block's atomics (all waves), then ARRIVE before repacking
  __syncthreads();
  if (arrive_cnt != nullptr && tid == 0) {
    __hip_atomic_fetch_add(arrive_cnt, 1u, __ATOMIC_RELAXED,
                           __HIP_MEMORY_SCOPE_AGENT);
  }

  if constexpr (!LAST) {
    for (int s = tid; s < 1536; s += 512) {
      int pix = s >> 5, c4 = s & 31;
      float4 sv = *(float4*)(ot + pix * LDO + c4 * 4);
      uint4 vv;
      vv.x = packhl(sv.x);
      vv.y = packhl(sv.y);
      vv.z = packhl(sv.z);
      vv.w = packhl(sv.w);
      // same 16 bytes we just read: LDO*4 == 264*2 == 528-byte rows
      *(uint4*)(xt + pix * 264 + c4 * 8) = vv;
    }
  }
}

// ---------------------------------------------------------------------------
// K2 FUSED, 512-thread blocks (8 waves): KNN+edge at 2 queries/wave
// (32 waves/CU during the VALU-bound knn phase — double the r7 TLP) ->
// X tile in LDS -> 3 VNT layers (8-wave variant) -> last-block merge.
// Per-query dv[32] lives for ONE query (register reuse, no spill — r9
// lesson); masks from the same bits that formed tval (r8 lesson).
// LDS union: knn view [spt 32768 | sphase 8x640] = 37888 B;
//            vnt view [xt 25344 | sb 3072 | spool 1536] = 29952 B.
// __launch_bounds__(512,8) caps VGPR at 64 -> 4 blocks/CU x 256 CUs = 1024
// blocks co-resident by construction (LDS 4x37888 = 151.5 KB <= 160 KB).
// ---------------------------------------------------------------------------
__global__ __launch_bounds__(512, 8) void fused_kernel(
    const float* __restrict__ pc, const float* __restrict__ Wpos,
    const float* __restrict__ Dp, float* __restrict__ ws,
    float* __restrict__ out) {
  __shared__ __align__(16) char U[37888];
  __shared__ unsigned int last_flag;
  int tid = threadIdx.x, wv = tid >> 6, lane = tid & 63;
  int bid = blockIdx.x;
  int b = bid >> 7;
  int nt = bid & 127;
  int p0 = nt * 48;

  float4* spt = (float4*)U;
  unsigned char* sph = (unsigned char*)(U + 32768) + wv * 640;
  unsigned short* sbufw = (unsigned short*)sph;
  float4* erw = (float4*)sph;
  unsigned short* xt = (unsigned short*)U;
  float* sb = (float*)(U + 25344);
  float* spool = (float*)(U + 28416);

  unsigned int* bar = (unsigned int*)(ws + OBAR);
  unsigned int* cnt1 = bar + b * 32;               // per-batch arrive, L1
  unsigned int* cnt2 = bar + 256 + b * 32;         // per-batch arrive, L2
  unsigned int* cntm = bar + 512;                  // global merge counter
  unsigned int* sbf2 = bar + 576 + b * 16;         // sb-published flag, L2
  unsigned int* sbf3 = bar + 704 + b * 16;         // sb-published flag, L3

  // hoisted edge-phase weight loads (latency hidden under spt staging)
  int o = lane;
  float w0 = Wpos[o * 3 + 0], w1 = Wpos[o * 3 + 1], w2 = Wpos[o * 3 + 2];
  float e0 = Dp[o * 3 + 0], e1 = Dp[o * 3 + 1], e2 = Dp[o * 3 + 2];

  // ---- stage point cloud ---------------------------------------------------
  const float* pcb = pc + (size_t)b * N * 3;
  for (int i = tid; i < N; i += 512) {
    float x = pcb[i * 3 + 0], y = pcb[i * 3 + 1], z = pcb[i * 3 + 2];
    float xx = __fadd_rn(__fadd_rn(__fmul_rn(x, x), __fmul_rn(y, y)), __fmul_rn(z, z));
    spt[i] = make_float4(2.f * x, 2.f * y, 2.f * z, xx);
  }
  __syncthreads();

  // normalize pos weights once (query-independent, exact same math)
  {
    float s = (w0 + w2) + w1;
    w0 = w0 / s; w1 = w1 / s; w2 = w2 / s;
  }

  unsigned rx0[2], rx1[2], rx2[2];  // packed edge-layer results per query

#pragma unroll
  for (int j = 0; j < 2; ++j) {
    int q = nt * 16 + wv * 2 + j;
    float4 qp = spt[q];
    float qx = 0.5f * qp.x, qy = 0.5f * qp.y, qz = 0.5f * qp.z, qxx = qp.w;

    float dv[32];
    float lmax = -INFINITY;
#pragma unroll
    for (int i = 0; i < 32; ++i) {
      float4 m = spt[i * 64 + lane];
      float A = __fadd_rn(__fadd_rn(__fmul_rn(m.x, qx), __fmul_rn(m.y, qy)),
                          __fmul_rn(m.z, qz));
      float d = __fsub_rn(__fsub_rn(A, qxx), m.w);
      dv[i] = d;
      lmax = fmaxf(lmax, d);
    }

    // value-only bitonic sort (descending) of the 64 lane-maxes; take #19
    float sv = lmax;
#pragma unroll
    for (int k = 2; k <= 64; k <<= 1) {
#pragma unroll
      for (int jj = k >> 1; jj > 0; jj >>= 1) {
        float pv = __shfl_xor(sv, jj);
        bool keep_max = ((lane & k) == 0) == ((lane & jj) == 0);
        sv = keep_max ? fmaxf(sv, pv) : fminf(sv, pv);
      }
    }
    float tval = __shfl(sv, 19);

    // registerized compact: per-lane survivor mask + shfl prefix scan
    unsigned msk = 0u;
#pragma unroll
    for (int i = 0; i < 32; ++i) msk |= (dv[i] >= tval) ? (1u << i) : 0u;
    int cnt = __popc(msk);
    int scan = cnt;
#pragma unroll
    for (int off = 1; off < 64; off <<= 1) {
      int t = __shfl_up(scan, off);
      scan += (lane >= off) ? t : 0;
    }
    int S = __shfl(scan, 63);
    int pos = scan - cnt;
    unsigned mm = msk;
    while (mm) {
      int i = __ffs(mm) - 1;
      mm &= mm - 1;
      if (pos < 192) sbufw[pos] = (unsigned short)(i * 64 + lane);
      ++pos;
    }

    auto distOf = [&](int m) -> float {
      float4 mp = spt[m];
      float A = __fadd_rn(__fadd_rn(__fmul_rn(mp.x, qx), __fmul_rn(mp.y, qy)),
                          __fmul_rn(mp.z, qz));
      return __fsub_rn(__fsub_rn(A, qxx), mp.w);
    };
    auto mkkey = [&](int m) -> unsigned long long {
      float d = distOf(m);
      unsigned u = __float_as_uint(d);
      u ^= (u >> 31) ? 0xFFFFFFFFu : 0x80000000u;
      return ((unsigned long long)u << 32) | (unsigned)(~m);
    };

    unsigned long long key = 0ULL;
    if (S <= 64) {
      if (lane < S) key = mkkey(sbufw[lane]);
      wave_sort_key(key, lane);
    } else if (S <= 192) {
      int p2 = 0;
      while (p2 < S) {
        if (lane >= KNN) {
          int t = p2 + lane - KNN;
          key = (t < S) ? mkkey(sbufw[t]) : 0ULL;
        }
        wave_sort_key(key, lane);
        p2 += 64 - KNN;
      }
    } else {
      int p2 = 0;
      while (p2 < N) {
        if (lane >= KNN) {
          int t = p2 + lane - KNN;
          key = (t < N) ? mkkey(t) : 0ULL;
        }
        wave_sort_key(key, lane);
        p2 += 64 - KNN;
      }
    }
    int cm = ~((unsigned)key);  // valid in lanes 0..19

    // edge geometry precompute: lane k<20 computes e/r once
    if (lane < KNN) {
      float4 t = spt[cm];
      float nx = 0.5f * t.x, ny = 0.5f * t.y, nz = 0.5f * t.z;
      float ex = nx - qx, ey = ny - qy, ez = nz - qz;
      float rrx = ny * qz - nz * qy;
      float rry = nz * qx - nx * qz;
      float rrz = nx * qy - ny * qx;
      erw[2 * lane + 0] = make_float4(ex, ey, ez, 0.f);
      erw[2 * lane + 1] = make_float4(rrx, rry, rrz, 0.f);
    }

    // edge + pos layer (lane o = channel o)
    float cx = qx, cy = qy, cz = qz;
    float pcx = w1 * cx, pcy = w1 * cy, pcz = w1 * cz;
    float dcx = e1 * cx, dcy = e1 * cy, dcz = e1 * cz;
    float ax = 0.f, ay = 0.f, az = 0.f;
#pragma unroll 4
    for (int k = 0; k < KNN; ++k) {
      float4 e4 = erw[2 * k + 0];
      float4 r4 = erw[2 * k + 1];
      float ex = e4.x, ey = e4.y, ez = e4.z;
      float rrx = r4.x, rry = r4.y, rrz = r4.z;
      float px = fmaf(w0, ex, fmaf(w2, rrx, pcx));
      float py = fmaf(w0, ey, fmaf(w2, rry, pcy));
      float pz = fmaf(w0, ez, fmaf(w2, rrz, pcz));
      float dx = fmaf(e0, ex, fmaf(e2, rrx, dcx));
      float dy = fmaf(e0, ey, fmaf(e2, rry, dcy));
      float dz = fmaf(e0, ez, fmaf(e2, rrz, dcz));
      float dot = fmaf(px, dx, fmaf(py, dy, pz * dz));
      float dns = fmaf(dx, dx, fmaf(dy, dy, dz * dz)) + 1e-6f;
      float r0 = __builtin_amdgcn_rcpf(dns);
      r0 = r0 * fmaf(-dns, r0, 2.0f);
      float f = (dot < 0.f) ? dot * r0 : 0.f;
      ax = fmaf(-f, dx, px) + ax;
      ay = fmaf(-f, dy, py) + ay;
      az = fmaf(-f, dz, pz) + az;
    }
    rx0[j] = packhl(ax * (1.f / 20.f));
    rx1[j] = packhl(ay * (1.f / 20.f));
    rx2[j] = packhl(az * (1.f / 20.f));
  }

  __syncthreads();  // spt/sphase dead everywhere; LDS becomes the X tile

  // write L1 X tile [48][128] bf16 hi/lo from registers (LDR = 136 halves)
#pragma unroll
  for (int j = 0; j < 2; ++j) {
    int row = wv * 2 + j;  // q & 15
    *(unsigned int*)(xt + (row + 0)  * 136 + 2 * o) = rx0[j];
    *(unsigned int*)(xt + (row + 16) * 136 + 2 * o) = rx1[j];
    *(unsigned int*)(xt + (row + 32) * 136 + 2 * o) = rx2[j];
  }
  // (tile-visibility barrier is inside the layer body)

  // layer1: K2=128, tile in LDS; arrive on cnt1; repack into LDS
  vnt_layer_body<128, false, false>(
      xt, sb, spool, (const unsigned short*)(ws + OWB1),
      nullptr, nullptr, nullptr, nullptr, ws + OPS1, nullptr,
      nullptr, cnt1, b, nt, p0, tid);

  // layer2: K2=256; leader (nt==0) waits cnt1, computes+publishes sb; arrive cnt2
  vnt_layer_body<256, true, false>(
      xt, sb, spool, (const unsigned short*)(ws + OWB2),
      ws + OPS1, ws + OWT2, ws + OSB2 + b * 768, sbf2, ws + OPS2, nullptr,
      cnt1, cnt2, b, nt, p0, tid);

  // layer3: K2=256; leader waits cnt2, publishes sb; outs shadows
  vnt_layer_body<256, true, true>(
      xt, sb, spool, (const unsigned short*)(ws + OWB3),
      ws + OPS2, ws + OWT3, ws + OSB3 + b * 768, sbf3, nullptr, ws + OOUTS,
      cnt2, nullptr, b, nt, p0, tid);

  // last-arriving block performs the merge; everyone else just exits.
  if (tid == 0) {
    unsigned old = __hip_atomic_fetch_add(cntm, 1u, __ATOMIC_RELAXED,
                                          __HIP_MEMORY_SCOPE_AGENT);
    last_flag = (old == (unsigned)GRID_VNT - 1) ? 1u : 0u;
  }
  __syncthreads();
  if (last_flag) {
    const float* outs = ws + OOUTS;
    for (int idx = tid; idx < B * 384; idx += 512) {
      float s = 0.f;
#pragma unroll
      for (int k = 0; k < 8; ++k) s += cohload(&outs[k * 3072 + idx]);
      out[idx] = s * (1.f / 2048.f);
    }
  }
}

// ---------------------------------------------------------------------------
// launch
// ---------------------------------------------------------------------------
extern "C" void kernel_launch(void* const* d_in, const int* in_sizes, int n_in,
                              void* d_out, int out_size, void* d_ws, size_t ws_size,
                              hipStream_t stream) {
  (void)in_sizes; (void)n_in; (void)out_size; (void)ws_size;
  const float* pc   = (const float*)d_in[0];
  const float* Wpos = (const float*)d_in[1];
  const float* Dpos = (const float*)d_in[2];
  const float* W1   = (const float*)d_in[3];
  const float* D1   = (const float*)d_in[4];
  const float* W2   = (const float*)d_in[5];
  const float* D2   = (const float*)d_in[6];
  const float* W3   = (const float*)d_in[7];
  const float* D3   = (const float*)d_in[8];
  float* out = (float*)d_out;
  float* ws  = (float*)d_ws;

  // K1: zero shadows/counters + pack weights (orders ahead of fused kernel)
  prep_kernel<<<PREP_BLOCKS, 256, 0, stream>>>(W1, D1, W2, D2, W3, D3, ws);

  // K2: fused KNN+edge+3-layer VNT stack + last-block merge (512-thread
  // blocks: 32 waves/CU during the VALU-bound knn phase)
  fused_kernel<<<GRID_VNT, 512, 0, stream>>>(pc, Wpos, Dpos, ws, out);
}

// Round 12
// 157.787 us; speedup vs baseline: 1.2224x; 1.2224x over previous
//
#include <hip/hip_runtime.h>
#include <hip/hip_bf16.h>
#include <math.h>

// ---------------------------------------------------------------------------
// Problem constants
// ---------------------------------------------------------------------------
constexpr int B = 8;
constexpr int N = 2048;
constexpr int KNN = 20;
constexpr int H = 128;
constexpr int P = 3 * N;  // 6144 pixels per batch

// ws layout (float offsets)
constexpr int OSB2   = 0;         // published sb for layer2 [B][768]
constexpr int OWT2   = 8448;      // W2/D2 second-half TRANSPOSED [c<128][m<256]
constexpr int OWT3   = 41216;     // W3/D3 second-half transposed
constexpr int OPS1   = 73984;     // poolsum1 shadows [8][B][128][3] = 24576
constexpr int OPS2   = 98560;     // poolsum2 shadows = 24576
constexpr int OOUTS  = 123136;    // out shadows [8][B][384] = 24576
constexpr int OBAR   = 147712;    // barrier counters/flags (1024 f reserved)
constexpr int OSB3   = 148736;    // published sb for layer3 [B][768]
constexpr int OWB1   = 160000;    // Wbig1 bf16 hi/lo, FRAGMENT-MAJOR (16384 f)
constexpr int OWB2   = 176384;    // Wbig2 fragment-major (32768 f)
constexpr int OWB3   = 209152;    // Wbig3 fragment-major (32768 f)

constexpr int ZERO_BASE = OPS1;   // zeroed region = ps1+ps2+outs+barriers
constexpr int ZERO_CNT  = 74752;  // 73728 shadows + 1024 barrier words
constexpr int PREP_BLOCKS = (ZERO_CNT + 255) / 256;  // 292

constexpr int GRID_VNT  = 1024;   // 4 blocks/CU x 256 CU, exactly co-resident
constexpr int BLK_PER_B = 128;    // blocks per batch (per-batch barrier target)

typedef __attribute__((ext_vector_type(8))) short bf16x8;
typedef __attribute__((ext_vector_type(4))) float f32x4;

__device__ __forceinline__ unsigned short f2bf(float x) {
  __hip_bfloat16 h = __float2bfloat16(x);
  return *(unsigned short*)&h;
}
__device__ __forceinline__ float bf2f(unsigned short u) {
  __hip_bfloat16 h;
  *(unsigned short*)&h = u;
  return __bfloat162float(h);
}
// pack x as (hi, lo) bf16 pair in one uint (hi at lower address)
__device__ __forceinline__ unsigned int packhl(float x) {
  unsigned short hi = f2bf(x);
  float lo = x - bf2f(hi);
  unsigned short ls = f2bf(lo);
  return (unsigned)hi | ((unsigned)ls << 16);
}

// coherent-point read/write (no cache-maintenance instructions)
__device__ __forceinline__ float cohload(const float* p) {
  return __hip_atomic_load(p, __ATOMIC_RELAXED, __HIP_MEMORY_SCOPE_AGENT);
}
__device__ __forceinline__ void cohstore(float* p, float v) {
  __hip_atomic_store(p, v, __ATOMIC_RELAXED, __HIP_MEMORY_SCOPE_AGENT);
}

// ---------------------------------------------------------------------------
// Wave-wide bitonic sort of 64 u64 keys, descending.
// ---------------------------------------------------------------------------
__device__ __forceinline__ void wave_sort_key(unsigned long long& k, int lane) {
#pragma unroll
  for (int kk = 2; kk <= 64; kk <<= 1) {
#pragma unroll
    for (int j = kk >> 1; j > 0; j >>= 1) {
      unsigned long long pk =
          (unsigned long long)__shfl_xor((long long)k, j);
      bool iam_lower   = (lane & j) == 0;
      bool dir_desc    = (lane & kk) == 0;
      bool p_better    = pk > k;
      bool want_better = (dir_desc == iam_lower);
      k = (p_better == want_better) ? pk : k;
    }
  }
}

// ---------------------------------------------------------------------------
// K1: prep — zero shadows/counters + pack weights.  Runs BEFORE the fused
// kernel; the kernel boundary orders zeroing/packing ahead of all barrier
// arrivals and Wb reads.
// ---------------------------------------------------------------------------
__global__ __launch_bounds__(256) void prep_kernel(
    const float* __restrict__ W1, const float* __restrict__ D1,
    const float* __restrict__ W2, const float* __restrict__ D2,
    const float* __restrict__ W3, const float* __restrict__ D3,
    float* __restrict__ ws) {
  int tid = threadIdx.x;
  int bid = blockIdx.x;
  {
    int zi = bid * 256 + tid;
    if (zi < ZERO_CNT) ws[ZERO_BASE + zi] = 0.f;
  }
  if (bid < 96) {
    int wv = tid >> 6, lane = tid & 63;
#pragma unroll
    for (int r = 0; r < 2; ++r) {
      int rr = bid * 8 + wv * 2 + r;  // 0..767
      const float* src;
      float* tdst = nullptr;
      unsigned int* pdst;
      int C, Cpack;
      bool norm;
      if (rr < 128)      { src = W1 + rr * 64;            C = 64;  Cpack = 64;  norm = true;
                           pdst = (unsigned int*)(ws + OWB1) + rr * 16; }
      else if (rr < 256) { int m = rr - 128; src = D1 + m * 64;  C = 64;  Cpack = 64;  norm = false;
                           pdst = (unsigned int*)(ws + OWB1) + (m + 128) * 16; }
      else if (rr < 384) { int m = rr - 256; src = W2 + m * 256; C = 256; Cpack = 128; norm = true;
                           pdst = (unsigned int*)(ws + OWB2) + m * 16; tdst = ws + OWT2 + m; }
      else if (rr < 512) { int m = rr - 384; src = D2 + m * 256; C = 256; Cpack = 128; norm = false;
                           pdst = (unsigned int*)(ws + OWB2) + (m + 128) * 16; tdst = ws + OWT2 + 128 + m; }
      else if (rr < 640) { int m = rr - 512; src = W3 + m * 256; C = 256; Cpack = 128; norm = true;
                           pdst = (unsigned int*)(ws + OWB3) + m * 16; tdst = ws + OWT3 + m; }
      else               { int m = rr - 640; src = D3 + m * 256; C = 256; Cpack = 128; norm = false;
                           pdst = (unsigned int*)(ws + OWB3) + (m + 128) * 16; tdst = ws + OWT3 + 128 + m; }
      float s = 1.f;
      if (norm) {
        float a = 0.f;
        for (int i = lane; i < C; i += 64) a += src[i];
#pragma unroll
        for (int off = 32; off > 0; off >>= 1) a += __shfl_xor(a, off);
        s = a;
      }
      for (int i = lane; i < C; i += 64) {
        float val = src[i] / s;  // exact when s==1
        if (i < Cpack) pdst[(i >> 4) * 4096 + (i & 15)] = packhl(val);
        if (tdst && i >= 128) tdst[(i - 128) * 256] = val;
      }
    }
  }
}

// ---------------------------------------------------------------------------
// Shared VNT layer body (X tile ALREADY in LDS).  Identical math/ordering to
// the verified per-layer kernel.  In-place repack valid because
// LDO*4 bytes == (256+8)*2 bytes == 528.
// ---------------------------------------------------------------------------
template <int K2, bool HASPOOL, bool LAST>
__device__ __forceinline__ void vnt_layer_body(
    unsigned short* xt, float* sb, float* spool,
    const unsigned short* __restrict__ Wb,
    const float* __restrict__ ps, const float* __restrict__ Wt,
    float* __restrict__ sbg, unsigned int* sbflag,
    float* __restrict__ pool, float* __restrict__ outs,
    unsigned int* wait_cnt, unsigned int* arrive_cnt,
    int b, int nt, int p0, int tid) {
  constexpr int KS = K2 / 32;
  constexpr int LDR = K2 + 8;   // halves; X-tile row stride
  constexpr int LDO = 132;      // floats; out-tile row stride
  float* ot = (float*)xt;
  int w = tid >> 6, lane = tid & 63;
  int q = lane >> 4, cl = lane & 15;

  // first A-fragments: global, LDS-independent -> issue before wait/barrier
  bf16x8 acur[2][2], anxt[2][2];
#pragma unroll
  for (int t = 0; t < 2; ++t)
#pragma unroll
    for (int pd = 0; pd < 2; ++pd)
      acur[t][pd] = *(const bf16x8*)(Wb +
          (size_t)(32 * w + 16 * t + 128 * pd + cl) * 32 + q * 8);

  if constexpr (HASPOOL) {
    if (nt == 0) {
      // ---- leader: wait for all batch peers' pool-adds --------------------
      if (tid == 0) {
        while (__hip_atomic_load(wait_cnt, __ATOMIC_RELAXED,
                                 __HIP_MEMORY_SCOPE_AGENT) < (unsigned)BLK_PER_B) {
          __builtin_amdgcn_s_sleep(2);
        }
      }
      __syncthreads();  // wait done + tile visible
      for (int i = tid; i < 384; i += 256) {
        float x = 0.f;
#pragma unroll
        for (int k = 0; k < 8; ++k)
          x += cohload(&ps[k * 3072 + b * 384 + i]);
        spool[i] = x * (1.f / 2048.f);
      }
      __syncthreads();
      // bias: thread == stacked row m (0..127 = Wn, 128..255 = D)
      float s0 = 0.f, s1 = 0.f, s2 = 0.f;
#pragma unroll 16
      for (int c = 0; c < 128; ++c) {
        float x = Wt[c * 256 + tid];
        s0 = fmaf(x, spool[c * 3 + 0], s0);
        s1 = fmaf(x, spool[c * 3 + 1], s1);
        s2 = fmaf(x, spool[c * 3 + 2], s2);
      }
      sb[tid * 3 + 0] = s0;
      sb[tid * 3 + 1] = s1;
      sb[tid * 3 + 2] = s2;
      cohstore(&sbg[tid * 3 + 0], s0);   // publish to batch peers
      cohstore(&sbg[tid * 3 + 1], s1);
      cohstore(&sbg[tid * 3 + 2], s2);
      __syncthreads();  // drains publish stores (vmcnt 0) + sb LDS visible
      if (tid == 0)
        __hip_atomic_fetch_add(sbflag, 1u, __ATOMIC_RELAXED,
                               __HIP_MEMORY_SCOPE_AGENT);
    } else {
      // ---- follower: wait for the leader's published bias -----------------
      if (tid == 0) {
        while (__hip_atomic_load(sbflag, __ATOMIC_RELAXED,
                                 __HIP_MEMORY_SCOPE_AGENT) < 1u) {
          __builtin_amdgcn_s_sleep(2);
        }
      }
      __syncthreads();  // flag seen + tile visible
      for (int i = tid; i < 768; i += 256) sb[i] = cohload(&sbg[i]);
      __syncthreads();  // sb in LDS for all waves
    }
  } else {
    __syncthreads();  // tile visible to all waves
  }

  f32x4 acc[2][2][3] = {};  // [t][pd][v]

#pragma unroll
  for (int ks = 0; ks < KS; ++ks) {
    if (ks + 1 < KS) {
#pragma unroll
      for (int t = 0; t < 2; ++t)
#pragma unroll
        for (int pd = 0; pd < 2; ++pd)
          anxt[t][pd] = *(const bf16x8*)(Wb +
              (size_t)(32 * w + 16 * t + 128 * pd + cl) * 32 + q * 8 +
              (ks + 1) * 8192);
    }
    bf16x8 bb[3];
#pragma unroll
    for (int v = 0; v < 3; ++v)
      bb[v] = *(const bf16x8*)(xt + (v * 16 + cl) * LDR + ks * 32 + q * 8);
#pragma unroll
    for (int t = 0; t < 2; ++t)
#pragma unroll
      for (int pd = 0; pd < 2; ++pd)
#pragma unroll
        for (int v = 0; v < 3; ++v)
          acc[t][pd][v] = __builtin_amdgcn_mfma_f32_16x16x32_bf16(
              acur[t][pd], bb[v], acc[t][pd][v], 0, 0, 0);
#pragma unroll
    for (int t = 0; t < 2; ++t)
#pragma unroll
      for (int pd = 0; pd < 2; ++pd)
        acur[t][pd] = anxt[t][pd];
  }
  __syncthreads();  // X-tile dead; buffer becomes the fp32 out-tile

#pragma unroll
  for (int t = 0; t < 2; ++t) {
    float res[3][4];
#pragma unroll
    for (int r = 0; r < 4; ++r) {
      int o = 32 * w + 16 * t + 4 * q + r;
      float pv[3], dvv[3];
#pragma unroll
      for (int v = 0; v < 3; ++v) {
        pv[v] = acc[t][0][v][r] + (HASPOOL ? sb[o * 3 + v] : 0.f);
        dvv[v] = acc[t][1][v][r] + (HASPOOL ? sb[(128 + o) * 3 + v] : 0.f);
      }
      float dot = fmaf(pv[0], dvv[0], fmaf(pv[1], dvv[1], pv[2] * dvv[2]));
      float dns = fmaf(dvv[0], dvv[0], fmaf(dvv[1], dvv[1], dvv[2] * dvv[2]));
      float f = (dot < 0.f) ? dot / (dns + 1e-6f) : 0.f;
#pragma unroll
      for (int v = 0; v < 3; ++v) res[v][r] = pv[v] - f * dvv[v];
    }
    int o0 = 32 * w + 16 * t + 4 * q;
#pragma unroll
    for (int v = 0; v < 3; ++v) {
      f32x4 rv = {res[v][0], res[v][1], res[v][2], res[v][3]};
      *(f32x4*)(ot + (v * 16 + cl) * LDO + o0) = rv;
    }
  }
  __syncthreads();

  int shadow = (nt & 7) * 3072;
  for (int s = tid; s < 384; s += 256) {
    int o = s / 3, v = s % 3;
    float a2 = 0.f;
#pragma unroll
    for (int c = 0; c < 16; ++c) a2 += ot[(v * 16 + c) * LDO + o];
    if (LAST) atomicAdd(outs + shadow + b * 384 + s, a2);
    else      atomicAdd(pool + shadow + b * 384 + s, a2);
  }

  // drain this block's atomics (all waves), then ARRIVE before repacking
  __syncthreads();
  if (arrive_cnt != nullptr && tid == 0) {
    __hip_atomic_fetch_add(arrive_cnt, 1u, __ATOMIC_RELAXED,
                           __HIP_MEMORY_SCOPE_AGENT);
  }

  if constexpr (!LAST) {
    for (int s = tid; s < 1536; s += 256) {
      int pix = s >> 5, c4 = s & 31;
      float4 sv = *(float4*)(ot + pix * LDO + c4 * 4);
      uint4 vv;
      vv.x = packhl(sv.x);
      vv.y = packhl(sv.y);
      vv.z = packhl(sv.z);
      vv.w = packhl(sv.w);
      // same 16 bytes we just read: LDO*4 == 264*2 == 528-byte rows
      *(uint4*)(xt + pix * 264 + c4 * 8) = vv;
    }
  }
}

// ---------------------------------------------------------------------------
// K2 FUSED (r10 structure + distance-pass prefetch): KNN+edge (16 queries/
// block, 4/wave sequential; per-query dv[32] lives for ONE query — register
// reuse, no spill [r9/r11 lesson]; masks from the same bits that formed tval
// [r8 lesson]).  NEW vs r10: the 32-iteration distance loop runs a manual
// 4-deep LDS prefetch pipeline (mreg[4], static i&3 indexing) — load->use
// distance ~4 iters covers most of the ~120cy ds_read latency at 4 waves/
// SIMD.  Compute sequence per loaded value unchanged -> bit-identical.
// +16 VGPR under the 128 cap of __launch_bounds__(256,4): no spill expected
// (tripwire: WRITE_SIZE >> 10 MB).
// LDS union: knn view [spt 32768 | sphase 4x640] = 35328 B;
//            vnt view [xt 25344 | sb 3072 | spool 1536] = 29952 B.
// 4 blocks/CU x 256 CUs = 1024 blocks co-resident by construction.
// ---------------------------------------------------------------------------
__global__ __launch_bounds__(256, 4) void fused_kernel(
    const float* __restrict__ pc, const float* __restrict__ Wpos,
    const float* __restrict__ Dp, float* __restrict__ ws,
    float* __restrict__ out) {
  __shared__ __align__(16) char U[35328];
  __shared__ unsigned int last_flag;
  int tid = threadIdx.x, wv = tid >> 6, lane = tid & 63;
  int bid = blockIdx.x;
  int b = bid >> 7;
  int nt = bid & 127;
  int p0 = nt * 48;

  float4* spt = (float4*)U;
  unsigned char* sph = (unsigned char*)(U + 32768) + wv * 640;
  unsigned short* sbufw = (unsigned short*)sph;
  float4* erw = (float4*)sph;
  unsigned short* xt = (unsigned short*)U;
  float* sb = (float*)(U + 25344);
  float* spool = (float*)(U + 28416);

  unsigned int* bar = (unsigned int*)(ws + OBAR);
  unsigned int* cnt1 = bar + b * 32;               // per-batch arrive, L1
  unsigned int* cnt2 = bar + 256 + b * 32;         // per-batch arrive, L2
  unsigned int* cntm = bar + 512;                  // global merge counter
  unsigned int* sbf2 = bar + 576 + b * 16;         // sb-published flag, L2
  unsigned int* sbf3 = bar + 704 + b * 16;         // sb-published flag, L3

  // hoisted edge-phase weight loads (latency hidden under spt staging)
  int o = lane;
  float w0 = Wpos[o * 3 + 0], w1 = Wpos[o * 3 + 1], w2 = Wpos[o * 3 + 2];
  float e0 = Dp[o * 3 + 0], e1 = Dp[o * 3 + 1], e2 = Dp[o * 3 + 2];

  // ---- stage point cloud ---------------------------------------------------
  const float* pcb = pc + (size_t)b * N * 3;
  for (int i = tid; i < N; i += 256) {
    float x = pcb[i * 3 + 0], y = pcb[i * 3 + 1], z = pcb[i * 3 + 2];
    float xx = __fadd_rn(__fadd_rn(__fmul_rn(x, x), __fmul_rn(y, y)), __fmul_rn(z, z));
    spt[i] = make_float4(2.f * x, 2.f * y, 2.f * z, xx);
  }
  __syncthreads();

  // normalize pos weights once (query-independent, exact same math)
  {
    float s = (w0 + w2) + w1;
    w0 = w0 / s; w1 = w1 / s; w2 = w2 / s;
  }

  unsigned rx0[4], rx1[4], rx2[4];  // packed edge-layer results per query

#pragma unroll
  for (int j = 0; j < 4; ++j) {
    int q = nt * 16 + wv * 4 + j;
    float4 qp = spt[q];
    float qx = 0.5f * qp.x, qy = 0.5f * qp.y, qz = 0.5f * qp.z, qxx = qp.w;

    // ---- distance pass with 4-deep LDS prefetch pipeline -------------------
    float dv[32];
    float lmax = -INFINITY;
    float4 mreg[4];
#pragma unroll
    for (int i = 0; i < 4; ++i) mreg[i] = spt[i * 64 + lane];
#pragma unroll
    for (int i = 0; i < 32; ++i) {
      float4 m = mreg[i & 3];
      if (i + 4 < 32) mreg[i & 3] = spt[(i + 4) * 64 + lane];
      float A = __fadd_rn(__fadd_rn(__fmul_rn(m.x, qx), __fmul_rn(m.y, qy)),
                          __fmul_rn(m.z, qz));
      float d = __fsub_rn(__fsub_rn(A, qxx), m.w);
      dv[i] = d;
      lmax = fmaxf(lmax, d);
    }

    // value-only bitonic sort (descending) of the 64 lane-maxes; take #19
    float sv = lmax;
#pragma unroll
    for (int k = 2; k <= 64; k <<= 1) {
#pragma unroll
      for (int jj = k >> 1; jj > 0; jj >>= 1) {
        float pv = __shfl_xor(sv, jj);
        bool keep_max = ((lane & k) == 0) == ((lane & jj) == 0);
        sv = keep_max ? fmaxf(sv, pv) : fminf(sv, pv);
      }
    }
    float tval = __shfl(sv, 19);

    // registerized compact: per-lane survivor mask + shfl prefix scan
    unsigned msk = 0u;
#pragma unroll
    for (int i = 0; i < 32; ++i) msk |= (dv[i] >= tval) ? (1u << i) : 0u;
    int cnt = __popc(msk);
    int scan = cnt;
#pragma unroll
    for (int off = 1; off < 64; off <<= 1) {
      int t = __shfl_up(scan, off);
      scan += (lane >= off) ? t : 0;
    }
    int S = __shfl(scan, 63);
    int pos = scan - cnt;
    unsigned mm = msk;
    while (mm) {
      int i = __ffs(mm) - 1;
      mm &= mm - 1;
      if (pos < 192) sbufw[pos] = (unsigned short)(i * 64 + lane);
      ++pos;
    }

    auto distOf = [&](int m) -> float {
      float4 mp = spt[m];
      float A = __fadd_rn(__fadd_rn(__fmul_rn(mp.x, qx), __fmul_rn(mp.y, qy)),
                          __fmul_rn(mp.z, qz));
      return __fsub_rn(__fsub_rn(A, qxx), mp.w);
    };
    auto mkkey = [&](int m) -> unsigned long long {
      float d = distOf(m);
      unsigned u = __float_as_uint(d);
      u ^= (u >> 31) ? 0xFFFFFFFFu : 0x80000000u;
      return ((unsigned long long)u << 32) | (unsigned)(~m);
    };

    unsigned long long key = 0ULL;
    if (S <= 64) {
      if (lane < S) key = mkkey(sbufw[lane]);
      wave_sort_key(key, lane);
    } else if (S <= 192) {
      int p2 = 0;
      while (p2 < S) {
        if (lane >= KNN) {
          int t = p2 + lane - KNN;
          key = (t < S) ? mkkey(sbufw[t]) : 0ULL;
        }
        wave_sort_key(key, lane);
        p2 += 64 - KNN;
      }
    } else {
      int p2 = 0;
      while (p2 < N) {
        if (lane >= KNN) {
          int t = p2 + lane - KNN;
          key = (t < N) ? mkkey(t) : 0ULL;
        }
        wave_sort_key(key, lane);
        p2 += 64 - KNN;
      }
    }
    int cm = ~((unsigned)key);  // valid in lanes 0..19

    // edge geometry precompute: lane k<20 computes e/r once
    if (lane < KNN) {
      float4 t = spt[cm];
      float nx = 0.5f * t.x, ny = 0.5f * t.y, nz = 0.5f * t.z;
      float ex = nx - qx, ey = ny - qy, ez = nz - qz;
      float rrx = ny * qz - nz * qy;
      float rry = nz * qx - nx * qz;
      float rrz = nx * qy - ny * qx;
      erw[2 * lane + 0] = make_float4(ex, ey, ez, 0.f);
      erw[2 * lane + 1] = make_float4(rrx, rry, rrz, 0.f);
    }

    // edge + pos layer (lane o = channel o)
    float cx = qx, cy = qy, cz = qz;
    float pcx = w1 * cx, pcy = w1 * cy, pcz = w1 * cz;
    float dcx = e1 * cx, dcy = e1 * cy, dcz = e1 * cz;
    float ax = 0.f, ay = 0.f, az = 0.f;
#pragma unroll 4
    for (int k = 0; k < KNN; ++k) {
      float4 e4 = erw[2 * k + 0];
      float4 r4 = erw[2 * k + 1];
      float ex = e4.x, ey = e4.y, ez = e4.z;
      float rrx = r4.x, rry = r4.y, rrz = r4.z;
      float px = fmaf(w0, ex, fmaf(w2, rrx, pcx));
      float py = fmaf(w0, ey, fmaf(w2, rry, pcy));
      float pz = fmaf(w0, ez, fmaf(w2, rrz, pcz));
      float dx = fmaf(e0, ex, fmaf(e2, rrx, dcx));
      float dy = fmaf(e0, ey, fmaf(e2, rry, dcy));
      float dz = fmaf(e0, ez, fmaf(e2, rrz, dcz));
      float dot = fmaf(px, dx, fmaf(py, dy, pz * dz));
      float dns = fmaf(dx, dx, fmaf(dy, dy, dz * dz)) + 1e-6f;
      float r0 = __builtin_amdgcn_rcpf(dns);
      r0 = r0 * fmaf(-dns, r0, 2.0f);
      float f = (dot < 0.f) ? dot * r0 : 0.f;
      ax = fmaf(-f, dx, px) + ax;
      ay = fmaf(-f, dy, py) + ay;
      az = fmaf(-f, dz, pz) + az;
    }
    rx0[j] = packhl(ax * (1.f / 20.f));
    rx1[j] = packhl(ay * (1.f / 20.f));
    rx2[j] = packhl(az * (1.f / 20.f));
  }

  __syncthreads();  // spt/sphase dead everywhere; LDS becomes the X tile

  // write L1 X tile [48][128] bf16 hi/lo from registers (LDR = 136 halves)
#pragma unroll
  for (int j = 0; j < 4; ++j) {
    int row = wv * 4 + j;  // q & 15
    *(unsigned int*)(xt + (row + 0)  * 136 + 2 * o) = rx0[j];
    *(unsigned int*)(xt + (row + 16) * 136 + 2 * o) = rx1[j];
    *(unsigned int*)(xt + (row + 32) * 136 + 2 * o) = rx2[j];
  }
  // (tile-visibility barrier is inside the layer body)

  // layer1: K2=128, tile in LDS; arrive on cnt1; repack into LDS
  vnt_layer_body<128, false, false>(
      xt, sb, spool, (const unsigned short*)(ws + OWB1),
      nullptr, nullptr, nullptr, nullptr, ws + OPS1, nullptr,
      nullptr, cnt1, b, nt, p0, tid);

  // layer2: K2=256; leader (nt==0) waits cnt1, computes+publishes sb; arrive cnt2
  vnt_layer_body<256, true, false>(
      xt, sb, spool, (const unsigned short*)(ws + OWB2),
      ws + OPS1, ws + OWT2, ws + OSB2 + b * 768, sbf2, ws + OPS2, nullptr,
      cnt1, cnt2, b, nt, p0, tid);

  // layer3: K2=256; leader waits cnt2, publishes sb; outs shadows
  vnt_layer_body<256, true, true>(
      xt, sb, spool, (const unsigned short*)(ws + OWB3),
      ws + OPS2, ws + OWT3, ws + OSB3 + b * 768, sbf3, nullptr, ws + OOUTS,
      cnt2, nullptr, b, nt, p0, tid);

  // last-arriving block performs the merge; everyone else just exits.
  if (tid == 0) {
    unsigned old = __hip_atomic_fetch_add(cntm, 1u, __ATOMIC_RELAXED,
                                          __HIP_MEMORY_SCOPE_AGENT);
    last_flag = (old == (unsigned)GRID_VNT - 1) ? 1u : 0u;
  }
  __syncthreads();
  if (last_flag) {
    const float* outs = ws + OOUTS;
    for (int idx = tid; idx < B * 384; idx += 256) {
      float s = 0.f;
#pragma unroll
      for (int k = 0; k < 8; ++k) s += cohload(&outs[k * 3072 + idx]);
      out[idx] = s * (1.f / 2048.f);
    }
  }
}

// ---------------------------------------------------------------------------
// launch
// ---------------------------------------------------------------------------
extern "C" void kernel_launch(void* const* d_in, const int* in_sizes, int n_in,
                              void* d_out, int out_size, void* d_ws, size_t ws_size,
                              hipStream_t stream) {
  (void)in_sizes; (void)n_in; (void)out_size; (void)ws_size;
  const float* pc   = (const float*)d_in[0];
  const float* Wpos = (const float*)d_in[1];
  const float* Dpos = (const float*)d_in[2];
  const float* W1   = (const float*)d_in[3];
  const float* D1   = (const float*)d_in[4];
  const float* W2   = (const float*)d_in[5];
  const float* D2   = (const float*)d_in[6];
  const float* W3   = (const float*)d_in[7];
  const float* D3   = (const float*)d_in[8];
  float* out = (float*)d_out;
  float* ws  = (float*)d_ws;

  // K1: zero shadows/counters + pack weights (orders ahead of fused kernel)
  prep_kernel<<<PREP_BLOCKS, 256, 0, stream>>>(W1, D1, W2, D2, W3, D3, ws);

  // K2: fused KNN+edge+3-layer VNT stack + last-block merge
  fused_kernel<<<GRID_VNT, 256, 0, stream>>>(pc, Wpos, Dpos, ws, out);
}

// Round 13
// 155.722 us; speedup vs baseline: 1.2386x; 1.0133x over previous
//
#include <hip/hip_runtime.h>
#include <hip/hip_bf16.h>
#include <math.h>

// ---------------------------------------------------------------------------
// Problem constants
// ---------------------------------------------------------------------------
constexpr int B = 8;
constexpr int N = 2048;
constexpr int KNN = 20;
constexpr int H = 128;
constexpr int P = 3 * N;  // 6144 pixels per batch

// ws layout (float offsets)
constexpr int OSB2   = 0;         // published sb for layer2 [B][768]
constexpr int OWT2   = 8448;      // W2/D2 second-half TRANSPOSED [c<128][m<256]
constexpr int OWT3   = 41216;     // W3/D3 second-half transposed
constexpr int OPS1   = 73984;     // poolsum1 shadows [8][B][128][3] = 24576
constexpr int OPS2   = 98560;     // poolsum2 shadows = 24576
constexpr int OOUTS  = 123136;    // out shadows [8][B][384] = 24576
constexpr int OBAR   = 147712;    // barrier counters/flags (1024 f reserved)
constexpr int OSB3   = 148736;    // published sb for layer3 [B][768]
constexpr int OWB1   = 160000;    // Wbig1 bf16 hi/lo, FRAGMENT-MAJOR (16384 f)
constexpr int OWB2   = 176384;    // Wbig2 fragment-major (32768 f)
constexpr int OWB3   = 209152;    // Wbig3 fragment-major (32768 f)

constexpr int ZERO_BASE = OPS1;   // zeroed region = ps1+ps2+outs+barriers
constexpr int ZERO_CNT  = 74752;  // 73728 shadows + 1024 barrier words
constexpr int PREP_BLOCKS = (ZERO_CNT + 255) / 256;  // 292

constexpr int GRID_VNT  = 1024;   // 4 blocks/CU x 256 CU, exactly co-resident
constexpr int BLK_PER_B = 128;    // blocks per batch (per-batch barrier target)

typedef __attribute__((ext_vector_type(8))) short bf16x8;
typedef __attribute__((ext_vector_type(4))) float f32x4;

__device__ __forceinline__ unsigned short f2bf(float x) {
  __hip_bfloat16 h = __float2bfloat16(x);
  return *(unsigned short*)&h;
}
__device__ __forceinline__ float bf2f(unsigned short u) {
  __hip_bfloat16 h;
  *(unsigned short*)&h = u;
  return __bfloat162float(h);
}
// pack x as (hi, lo) bf16 pair in one uint (hi at lower address)
__device__ __forceinline__ unsigned int packhl(float x) {
  unsigned short hi = f2bf(x);
  float lo = x - bf2f(hi);
  unsigned short ls = f2bf(lo);
  return (unsigned)hi | ((unsigned)ls << 16);
}

// coherent-point read/write (no cache-maintenance instructions)
__device__ __forceinline__ float cohload(const float* p) {
  return __hip_atomic_load(p, __ATOMIC_RELAXED, __HIP_MEMORY_SCOPE_AGENT);
}
__device__ __forceinline__ void cohstore(float* p, float v) {
  __hip_atomic_store(p, v, __ATOMIC_RELAXED, __HIP_MEMORY_SCOPE_AGENT);
}

// ---------------------------------------------------------------------------
// Interleaved wave-wide bitonic sort of TWO independent u64 key sets,
// descending.  Two independent shfl->cmp->sel chains per step -> 2x ILP on
// the latency-bound sort (the two sorts are bit-identical to running
// wave_sort_key twice serially: no cross-key interaction).
// ---------------------------------------------------------------------------
__device__ __forceinline__ void wave_sort_key2(unsigned long long& a,
                                               unsigned long long& b,
                                               int lane) {
#pragma unroll
  for (int kk = 2; kk <= 64; kk <<= 1) {
#pragma unroll
    for (int j = kk >> 1; j > 0; j >>= 1) {
      unsigned long long pa =
          (unsigned long long)__shfl_xor((long long)a, j);
      unsigned long long pb =
          (unsigned long long)__shfl_xor((long long)b, j);
      bool iam_lower   = (lane & j) == 0;
      bool dir_desc    = (lane & kk) == 0;
      bool want_better = (dir_desc == iam_lower);
      bool pa_better = pa > a;
      bool pb_better = pb > b;
      a = (pa_better == want_better) ? pa : a;
      b = (pb_better == want_better) ? pb : b;
    }
  }
}

// ---------------------------------------------------------------------------
// K1: prep — zero shadows/counters + pack weights.  Runs BEFORE the fused
// kernel; the kernel boundary orders zeroing/packing ahead of all barrier
// arrivals and Wb reads.
// ---------------------------------------------------------------------------
__global__ __launch_bounds__(256) void prep_kernel(
    const float* __restrict__ W1, const float* __restrict__ D1,
    const float* __restrict__ W2, const float* __restrict__ D2,
    const float* __restrict__ W3, const float* __restrict__ D3,
    float* __restrict__ ws) {
  int tid = threadIdx.x;
  int bid = blockIdx.x;
  {
    int zi = bid * 256 + tid;
    if (zi < ZERO_CNT) ws[ZERO_BASE + zi] = 0.f;
  }
  if (bid < 96) {
    int wv = tid >> 6, lane = tid & 63;
#pragma unroll
    for (int r = 0; r < 2; ++r) {
      int rr = bid * 8 + wv * 2 + r;  // 0..767
      const float* src;
      float* tdst = nullptr;
      unsigned int* pdst;
      int C, Cpack;
      bool norm;
      if (rr < 128)      { src = W1 + rr * 64;            C = 64;  Cpack = 64;  norm = true;
                           pdst = (unsigned int*)(ws + OWB1) + rr * 16; }
      else if (rr < 256) { int m = rr - 128; src = D1 + m * 64;  C = 64;  Cpack = 64;  norm = false;
                           pdst = (unsigned int*)(ws + OWB1) + (m + 128) * 16; }
      else if (rr < 384) { int m = rr - 256; src = W2 + m * 256; C = 256; Cpack = 128; norm = true;
                           pdst = (unsigned int*)(ws + OWB2) + m * 16; tdst = ws + OWT2 + m; }
      else if (rr < 512) { int m = rr - 384; src = D2 + m * 256; C = 256; Cpack = 128; norm = false;
                           pdst = (unsigned int*)(ws + OWB2) + (m + 128) * 16; tdst = ws + OWT2 + 128 + m; }
      else if (rr < 640) { int m = rr - 512; src = W3 + m * 256; C = 256; Cpack = 128; norm = true;
                           pdst = (unsigned int*)(ws + OWB3) + m * 16; tdst = ws + OWT3 + m; }
      else               { int m = rr - 640; src = D3 + m * 256; C = 256; Cpack = 128; norm = false;
                           pdst = (unsigned int*)(ws + OWB3) + (m + 128) * 16; tdst = ws + OWT3 + 128 + m; }
      float s = 1.f;
      if (norm) {
        float a = 0.f;
        for (int i = lane; i < C; i += 64) a += src[i];
#pragma unroll
        for (int off = 32; off > 0; off >>= 1) a += __shfl_xor(a, off);
        s = a;
      }
      for (int i = lane; i < C; i += 64) {
        float val = src[i] / s;  // exact when s==1
        if (i < Cpack) pdst[(i >> 4) * 4096 + (i & 15)] = packhl(val);
        if (tdst && i >= 128) tdst[(i - 128) * 256] = val;
      }
    }
  }
}

// ---------------------------------------------------------------------------
// Shared VNT layer body (X tile ALREADY in LDS).  Identical math/ordering to
// the verified per-layer kernel.  In-place repack valid because
// LDO*4 bytes == (256+8)*2 bytes == 528.
// ---------------------------------------------------------------------------
template <int K2, bool HASPOOL, bool LAST>
__device__ __forceinline__ void vnt_layer_body(
    unsigned short* xt, float* sb, float* spool,
    const unsigned short* __restrict__ Wb,
    const float* __restrict__ ps, const float* __restrict__ Wt,
    float* __restrict__ sbg, unsigned int* sbflag,
    float* __restrict__ pool, float* __restrict__ outs,
    unsigned int* wait_cnt, unsigned int* arrive_cnt,
    int b, int nt, int p0, int tid) {
  constexpr int KS = K2 / 32;
  constexpr int LDR = K2 + 8;   // halves; X-tile row stride
  constexpr int LDO = 132;      // floats; out-tile row stride
  float* ot = (float*)xt;
  int w = tid >> 6, lane = tid & 63;
  int q = lane >> 4, cl = lane & 15;

  // first A-fragments: global, LDS-independent -> issue before wait/barrier
  bf16x8 acur[2][2], anxt[2][2];
#pragma unroll
  for (int t = 0; t < 2; ++t)
#pragma unroll
    for (int pd = 0; pd < 2; ++pd)
      acur[t][pd] = *(const bf16x8*)(Wb +
          (size_t)(32 * w + 16 * t + 128 * pd + cl) * 32 + q * 8);

  if constexpr (HASPOOL) {
    if (nt == 0) {
      // ---- leader: wait for all batch peers' pool-adds --------------------
      if (tid == 0) {
        while (__hip_atomic_load(wait_cnt, __ATOMIC_RELAXED,
                                 __HIP_MEMORY_SCOPE_AGENT) < (unsigned)BLK_PER_B) {
          __builtin_amdgcn_s_sleep(2);
        }
      }
      __syncthreads();  // wait done + tile visible
      for (int i = tid; i < 384; i += 256) {
        float x = 0.f;
#pragma unroll
        for (int k = 0; k < 8; ++k)
          x += cohload(&ps[k * 3072 + b * 384 + i]);
        spool[i] = x * (1.f / 2048.f);
      }
      __syncthreads();
      // bias: thread == stacked row m (0..127 = Wn, 128..255 = D)
      float s0 = 0.f, s1 = 0.f, s2 = 0.f;
#pragma unroll 16
      for (int c = 0; c < 128; ++c) {
        float x = Wt[c * 256 + tid];
        s0 = fmaf(x, spool[c * 3 + 0], s0);
        s1 = fmaf(x, spool[c * 3 + 1], s1);
        s2 = fmaf(x, spool[c * 3 + 2], s2);
      }
      sb[tid * 3 + 0] = s0;
      sb[tid * 3 + 1] = s1;
      sb[tid * 3 + 2] = s2;
      cohstore(&sbg[tid * 3 + 0], s0);   // publish to batch peers
      cohstore(&sbg[tid * 3 + 1], s1);
      cohstore(&sbg[tid * 3 + 2], s2);
      __syncthreads();  // drains publish stores (vmcnt 0) + sb LDS visible
      if (tid == 0)
        __hip_atomic_fetch_add(sbflag, 1u, __ATOMIC_RELAXED,
                               __HIP_MEMORY_SCOPE_AGENT);
    } else {
      // ---- follower: wait for the leader's published bias -----------------
      if (tid == 0) {
        while (__hip_atomic_load(sbflag, __ATOMIC_RELAXED,
                                 __HIP_MEMORY_SCOPE_AGENT) < 1u) {
          __builtin_amdgcn_s_sleep(2);
        }
      }
      __syncthreads();  // flag seen + tile visible
      for (int i = tid; i < 768; i += 256) sb[i] = cohload(&sbg[i]);
      __syncthreads();  // sb in LDS for all waves
    }
  } else {
    __syncthreads();  // tile visible to all waves
  }

  f32x4 acc[2][2][3] = {};  // [t][pd][v]

#pragma unroll
  for (int ks = 0; ks < KS; ++ks) {
    if (ks + 1 < KS) {
#pragma unroll
      for (int t = 0; t < 2; ++t)
#pragma unroll
        for (int pd = 0; pd < 2; ++pd)
          anxt[t][pd] = *(const bf16x8*)(Wb +
              (size_t)(32 * w + 16 * t + 128 * pd + cl) * 32 + q * 8 +
              (ks + 1) * 8192);
    }
    bf16x8 bb[3];
#pragma unroll
    for (int v = 0; v < 3; ++v)
      bb[v] = *(const bf16x8*)(xt + (v * 16 + cl) * LDR + ks * 32 + q * 8);
#pragma unroll
    for (int t = 0; t < 2; ++t)
#pragma unroll
      for (int pd = 0; pd < 2; ++pd)
#pragma unroll
        for (int v = 0; v < 3; ++v)
          acc[t][pd][v] = __builtin_amdgcn_mfma_f32_16x16x32_bf16(
              acur[t][pd], bb[v], acc[t][pd][v], 0, 0, 0);
#pragma unroll
    for (int t = 0; t < 2; ++t)
#pragma unroll
      for (int pd = 0; pd < 2; ++pd)
        acur[t][pd] = anxt[t][pd];
  }
  __syncthreads();  // X-tile dead; buffer becomes the fp32 out-tile

#pragma unroll
  for (int t = 0; t < 2; ++t) {
    float res[3][4];
#pragma unroll
    for (int r = 0; r < 4; ++r) {
      int o = 32 * w + 16 * t + 4 * q + r;
      float pv[3], dvv[3];
#pragma unroll
      for (int v = 0; v < 3; ++v) {
        pv[v] = acc[t][0][v][r] + (HASPOOL ? sb[o * 3 + v] : 0.f);
        dvv[v] = acc[t][1][v][r] + (HASPOOL ? sb[(128 + o) * 3 + v] : 0.f);
      }
      float dot = fmaf(pv[0], dvv[0], fmaf(pv[1], dvv[1], pv[2] * dvv[2]));
      float dns = fmaf(dvv[0], dvv[0], fmaf(dvv[1], dvv[1], dvv[2] * dvv[2]));
      float f = (dot < 0.f) ? dot / (dns + 1e-6f) : 0.f;
#pragma unroll
      for (int v = 0; v < 3; ++v) res[v][r] = pv[v] - f * dvv[v];
    }
    int o0 = 32 * w + 16 * t + 4 * q;
#pragma unroll
    for (int v = 0; v < 3; ++v) {
      f32x4 rv = {res[v][0], res[v][1], res[v][2], res[v][3]};
      *(f32x4*)(ot + (v * 16 + cl) * LDO + o0) = rv;
    }
  }
  __syncthreads();

  int shadow = (nt & 7) * 3072;
  for (int s = tid; s < 384; s += 256) {
    int o = s / 3, v = s % 3;
    float a2 = 0.f;
#pragma unroll
    for (int c = 0; c < 16; ++c) a2 += ot[(v * 16 + c) * LDO + o];
    if (LAST) atomicAdd(outs + shadow + b * 384 + s, a2);
    else      atomicAdd(pool + shadow + b * 384 + s, a2);
  }

  // drain this block's atomics (all waves), then ARRIVE before repacking
  __syncthreads();
  if (arrive_cnt != nullptr && tid == 0) {
    __hip_atomic_fetch_add(arrive_cnt, 1u, __ATOMIC_RELAXED,
                           __HIP_MEMORY_SCOPE_AGENT);
  }

  if constexpr (!LAST) {
    for (int s = tid; s < 1536; s += 256) {
      int pix = s >> 5, c4 = s & 31;
      float4 sv = *(float4*)(ot + pix * LDO + c4 * 4);
      uint4 vv;
      vv.x = packhl(sv.x);
      vv.y = packhl(sv.y);
      vv.z = packhl(sv.z);
      vv.w = packhl(sv.w);
      // same 16 bytes we just read: LDO*4 == 264*2 == 528-byte rows
      *(uint4*)(xt + pix * 264 + c4 * 8) = vv;
    }
  }
}

// ---------------------------------------------------------------------------
// K2 FUSED (r10 structure + pair-interleaved top-k): KNN+edge (16 queries/
// block, 4/wave).  Distance/threshold/mask/compact remain strictly serial
// per query: dv[32] lives for ONE query (no spill — r9/r11 lesson), masks
// from the stored bits that formed tval (r8 lesson).  NEW: the exact-top-20
// sorts of each query PAIR run through one unified incremental loop with
// interleaved bitonic chains (wave_sort_key2) — provably bit-identical:
// exact top-20 selection is path-independent (unique keys, deterministic
// bitonic order, zero-padding iterations can't displace real keys), and the
// r10 S<=64 / S<=192 / scan-N paths all produce the same sorted top-20.
// Per-wave 320-entry compact buffer splits 2x160; S in (160,192] now takes
// the scan-all-N route (same exact selection -> same bits).
// LDS union: knn view [spt 32768 | sphase 4x640] = 35328 B;
//            vnt view [xt 25344 | sb 3072 | spool 1536] = 29952 B.
// 4 blocks/CU x 256 CUs = 1024 blocks co-resident by construction.
// Spill tripwire: WRITE_SIZE >> 10 MB.
// ---------------------------------------------------------------------------
__global__ __launch_bounds__(256, 4) void fused_kernel(
    const float* __restrict__ pc, const float* __restrict__ Wpos,
    const float* __restrict__ Dp, float* __restrict__ ws,
    float* __restrict__ out) {
  __shared__ __align__(16) char U[35328];
  __shared__ unsigned int last_flag;
  int tid = threadIdx.x, wv = tid >> 6, lane = tid & 63;
  int bid = blockIdx.x;
  int b = bid >> 7;
  int nt = bid & 127;
  int p0 = nt * 48;

  float4* spt = (float4*)U;
  unsigned char* sph = (unsigned char*)(U + 32768) + wv * 640;
  unsigned short* sbufw = (unsigned short*)sph;   // 320 u16 entries/wave
  float4* erw = (float4*)sph;                     // aliases sbufw (post-topk)
  unsigned short* xt = (unsigned short*)U;
  float* sb = (float*)(U + 25344);
  float* spool = (float*)(U + 28416);

  unsigned int* bar = (unsigned int*)(ws + OBAR);
  unsigned int* cnt1 = bar + b * 32;               // per-batch arrive, L1
  unsigned int* cnt2 = bar + 256 + b * 32;         // per-batch arrive, L2
  unsigned int* cntm = bar + 512;                  // global merge counter
  unsigned int* sbf2 = bar + 576 + b * 16;         // sb-published flag, L2
  unsigned int* sbf3 = bar + 704 + b * 16;         // sb-published flag, L3

  // hoisted edge-phase weight loads (latency hidden under spt staging)
  int o = lane;
  float w0 = Wpos[o * 3 + 0], w1 = Wpos[o * 3 + 1], w2 = Wpos[o * 3 + 2];
  float e0 = Dp[o * 3 + 0], e1 = Dp[o * 3 + 1], e2 = Dp[o * 3 + 2];

  // ---- stage point cloud ---------------------------------------------------
  const float* pcb = pc + (size_t)b * N * 3;
  for (int i = tid; i < N; i += 256) {
    float x = pcb[i * 3 + 0], y = pcb[i * 3 + 1], z = pcb[i * 3 + 2];
    float xx = __fadd_rn(__fadd_rn(__fmul_rn(x, x), __fmul_rn(y, y)), __fmul_rn(z, z));
    spt[i] = make_float4(2.f * x, 2.f * y, 2.f * z, xx);
  }
  __syncthreads();

  // normalize pos weights once (query-independent, exact same math)
  {
    float s = (w0 + w2) + w1;
    w0 = w0 / s; w1 = w1 / s; w2 = w2 / s;
  }

  unsigned rx0[4], rx1[4], rx2[4];  // packed edge-layer results per query

  // per-query prep: distance (stored dv), threshold sort, mask from stored
  // bits, compact into sbufw[bufOff..bufOff+160).  Returns S.
  auto prep_query = [&](int q, int bufOff,
                        float& qx, float& qy, float& qz, float& qxx) -> int {
    float4 qp = spt[q];
    qx = 0.5f * qp.x; qy = 0.5f * qp.y; qz = 0.5f * qp.z; qxx = qp.w;
    float dv[32];
    float lmax = -INFINITY;
#pragma unroll
    for (int i = 0; i < 32; ++i) {
      float4 m = spt[i * 64 + lane];
      float A = __fadd_rn(__fadd_rn(__fmul_rn(m.x, qx), __fmul_rn(m.y, qy)),
                          __fmul_rn(m.z, qz));
      float d = __fsub_rn(__fsub_rn(A, qxx), m.w);
      dv[i] = d;
      lmax = fmaxf(lmax, d);
    }
    // value-only bitonic sort (descending) of the 64 lane-maxes; take #19
    float sv = lmax;
#pragma unroll
    for (int k = 2; k <= 64; k <<= 1) {
#pragma unroll
      for (int jj = k >> 1; jj > 0; jj >>= 1) {
        float pv = __shfl_xor(sv, jj);
        bool keep_max = ((lane & k) == 0) == ((lane & jj) == 0);
        sv = keep_max ? fmaxf(sv, pv) : fminf(sv, pv);
      }
    }
    float tval = __shfl(sv, 19);  // 20th-largest lane-max <= V20 (provable)
    // mask from the STORED distances — same bits that formed tval
    unsigned msk = 0u;
#pragma unroll
    for (int i = 0; i < 32; ++i) msk |= (dv[i] >= tval) ? (1u << i) : 0u;
    int cnt = __popc(msk);
    int scan = cnt;
#pragma unroll
    for (int off = 1; off < 64; off <<= 1) {
      int t = __shfl_up(scan, off);
      scan += (lane >= off) ? t : 0;
    }
    int S = __shfl(scan, 63);
    int pos = scan - cnt;
    unsigned mm = msk;
    while (mm) {
      int i = __ffs(mm) - 1;
      mm &= mm - 1;
      if (pos < 160) sbufw[bufOff + pos] = (unsigned short)(i * 64 + lane);
      ++pos;
    }
    return S;
  };

  // edge + pos layer for one query (erw reused; clobbers compact buffers,
  // which are dead once the pair's top-k loop has completed)
  auto edge_query = [&](float qx, float qy, float qz, int cm,
                        unsigned& r0o, unsigned& r1o, unsigned& r2o) {
    if (lane < KNN) {
      float4 t = spt[cm];
      float nx = 0.5f * t.x, ny = 0.5f * t.y, nz = 0.5f * t.z;
      float ex = nx - qx, ey = ny - qy, ez = nz - qz;
      float rrx = ny * qz - nz * qy;
      float rry = nz * qx - nx * qz;
      float rrz = nx * qy - ny * qx;
      erw[2 * lane + 0] = make_float4(ex, ey, ez, 0.f);
      erw[2 * lane + 1] = make_float4(rrx, rry, rrz, 0.f);
    }
    float cx = qx, cy = qy, cz = qz;
    float pcx = w1 * cx, pcy = w1 * cy, pcz = w1 * cz;
    float dcx = e1 * cx, dcy = e1 * cy, dcz = e1 * cz;
    float ax = 0.f, ay = 0.f, az = 0.f;
#pragma unroll 4
    for (int k = 0; k < KNN; ++k) {
      float4 e4 = erw[2 * k + 0];
      float4 r4 = erw[2 * k + 1];
      float ex = e4.x, ey = e4.y, ez = e4.z;
      float rrx = r4.x, rry = r4.y, rrz = r4.z;
      float px = fmaf(w0, ex, fmaf(w2, rrx, pcx));
      float py = fmaf(w0, ey, fmaf(w2, rry, pcy));
      float pz = fmaf(w0, ez, fmaf(w2, rrz, pcz));
      float dx = fmaf(e0, ex, fmaf(e2, rrx, dcx));
      float dy = fmaf(e0, ey, fmaf(e2, rry, dcy));
      float dz = fmaf(e0, ez, fmaf(e2, rrz, dcz));
      float dot = fmaf(px, dx, fmaf(py, dy, pz * dz));
      float dns = fmaf(dx, dx, fmaf(dy, dy, dz * dz)) + 1e-6f;
      float r0 = __builtin_amdgcn_rcpf(dns);
      r0 = r0 * fmaf(-dns, r0, 2.0f);
      float f = (dot < 0.f) ? dot * r0 : 0.f;
      ax = fmaf(-f, dx, px) + ax;
      ay = fmaf(-f, dy, py) + ay;
      az = fmaf(-f, dz, pz) + az;
    }
    r0o = packhl(ax * (1.f / 20.f));
    r1o = packhl(ay * (1.f / 20.f));
    r2o = packhl(az * (1.f / 20.f));
  };

#pragma unroll
  for (int jp = 0; jp < 2; ++jp) {
    int qA = nt * 16 + wv * 4 + 2 * jp;
    int qB = qA + 1;
    float qxA, qyA, qzA, qxxA, qxB, qyB, qzB, qxxB;
    int SA = prep_query(qA, 0,   qxA, qyA, qzA, qxxA);
    int SB = prep_query(qB, 160, qxB, qyB, qzB, qxxB);

    // unified incremental exact-top-20 for BOTH queries, sorts interleaved.
    int Ca = (SA <= 160) ? SA : N;
    int Cb = (SB <= 160) ? SB : N;
    int Cm = (Ca > Cb) ? Ca : Cb;
    unsigned long long ka = 0ULL, kb = 0ULL;
    for (int p2 = 0; p2 < Cm; p2 += 64 - KNN) {
      if (lane >= KNN) {
        int t = p2 + lane - KNN;
        unsigned long long nk = 0ULL;
        if (t < Ca) {
          int m = (SA <= 160) ? (int)sbufw[t] : t;
          float4 mp = spt[m];
          float A = __fadd_rn(__fadd_rn(__fmul_rn(mp.x, qxA), __fmul_rn(mp.y, qyA)),
                              __fmul_rn(mp.z, qzA));
          float d = __fsub_rn(__fsub_rn(A, qxxA), mp.w);
          unsigned u = __float_as_uint(d);
          u ^= (u >> 31) ? 0xFFFFFFFFu : 0x80000000u;
          nk = ((unsigned long long)u << 32) | (unsigned)(~m);
        }
        ka = nk;
        nk = 0ULL;
        if (t < Cb) {
          int m = (SB <= 160) ? (int)sbufw[160 + t] : t;
          float4 mp = spt[m];
          float A = __fadd_rn(__fadd_rn(__fmul_rn(mp.x, qxB), __fmul_rn(mp.y, qyB)),
                              __fmul_rn(mp.z, qzB));
          float d = __fsub_rn(__fsub_rn(A, qxxB), mp.w);
          unsigned u = __float_as_uint(d);
          u ^= (u >> 31) ? 0xFFFFFFFFu : 0x80000000u;
          nk = ((unsigned long long)u << 32) | (unsigned)(~m);
        }
        kb = nk;
      }
      wave_sort_key2(ka, kb, lane);
    }
    int cmA = ~((unsigned)ka);  // valid in lanes 0..19
    int cmB = ~((unsigned)kb);

    // edge phases (serial; erw buffer reused — compact lists are dead)
    edge_query(qxA, qyA, qzA, cmA, rx0[2 * jp], rx1[2 * jp], rx2[2 * jp]);
    edge_query(qxB, qyB, qzB, cmB, rx0[2 * jp + 1], rx1[2 * jp + 1], rx2[2 * jp + 1]);
  }

  __syncthreads();  // spt/sphase dead everywhere; LDS becomes the X tile

  // write L1 X tile [48][128] bf16 hi/lo from registers (LDR = 136 halves)
#pragma unroll
  for (int j = 0; j < 4; ++j) {
    int row = wv * 4 + j;  // q & 15
    *(unsigned int*)(xt + (row + 0)  * 136 + 2 * o) = rx0[j];
    *(unsigned int*)(xt + (row + 16) * 136 + 2 * o) = rx1[j];
    *(unsigned int*)(xt + (row + 32) * 136 + 2 * o) = rx2[j];
  }
  // (tile-visibility barrier is inside the layer body)

  // layer1: K2=128, tile in LDS; arrive on cnt1; repack into LDS
  vnt_layer_body<128, false, false>(
      xt, sb, spool, (const unsigned short*)(ws + OWB1),
      nullptr, nullptr, nullptr, nullptr, ws + OPS1, nullptr,
      nullptr, cnt1, b, nt, p0, tid);

  // layer2: K2=256; leader (nt==0) waits cnt1, computes+publishes sb; arrive cnt2
  vnt_layer_body<256, true, false>(
      xt, sb, spool, (const unsigned short*)(ws + OWB2),
      ws + OPS1, ws + OWT2, ws + OSB2 + b * 768, sbf2, ws + OPS2, nullptr,
      cnt1, cnt2, b, nt, p0, tid);

  // layer3: K2=256; leader waits cnt2, publishes sb; outs shadows
  vnt_layer_body<256, true, true>(
      xt, sb, spool, (const unsigned short*)(ws + OWB3),
      ws + OPS2, ws + OWT3, ws + OSB3 + b * 768, sbf3, nullptr, ws + OOUTS,
      cnt2, nullptr, b, nt, p0, tid);

  // last-arriving block performs the merge; everyone else just exits.
  if (tid == 0) {
    unsigned old = __hip_atomic_fetch_add(cntm, 1u, __ATOMIC_RELAXED,
                                          __HIP_MEMORY_SCOPE_AGENT);
    last_flag = (old == (unsigned)GRID_VNT - 1) ? 1u : 0u;
  }
  __syncthreads();
  if (last_flag) {
    const float* outs = ws + OOUTS;
    for (int idx = tid; idx < B * 384; idx += 256) {
      float s = 0.f;
#pragma unroll
      for (int k = 0; k < 8; ++k) s += cohload(&outs[k * 3072 + idx]);
      out[idx] = s * (1.f / 2048.f);
    }
  }
}

// ---------------------------------------------------------------------------
// launch
// ---------------------------------------------------------------------------
extern "C" void kernel_launch(void* const* d_in, const int* in_sizes, int n_in,
                              void* d_out, int out_size, void* d_ws, size_t ws_size,
                              hipStream_t stream) {
  (void)in_sizes; (void)n_in; (void)out_size; (void)ws_size;
  const float* pc   = (const float*)d_in[0];
  const float* Wpos = (const float*)d_in[1];
  const float* Dpos = (const float*)d_in[2];
  const float* W1   = (const float*)d_in[3];
  const float* D1   = (const float*)d_in[4];
  const float* W2   = (const float*)d_in[5];
  const float* D2   = (const float*)d_in[6];
  const float* W3   = (const float*)d_in[7];
  const float* D3   = (const float*)d_in[8];
  float* out = (float*)d_out;
  float* ws  = (float*)d_ws;

  // K1: zero shadows/counters + pack weights (orders ahead of fused kernel)
  prep_kernel<<<PREP_BLOCKS, 256, 0, stream>>>(W1, D1, W2, D2, W3, D3, ws);

  // K2: fused KNN+edge+3-layer VNT stack + last-block merge
  fused_kernel<<<GRID_VNT, 256, 0, stream>>>(pc, Wpos, Dpos, ws, out);
}